// Round 5
// baseline (707.516 us; speedup 1.0000x reference)
//
#include <hip/hip_runtime.h>

#define N_NODES 50000
#define N_EDGES 800000
#define IN_CH   151
#define HID     128
#define OUT_CH  51
#define EDIM    51
#define SSTR    52              // padded S row stride (floats): 51 + 1 pad -> 208B rows
#define WP      64              // padded minor dim for Wc / Mc / w
#define LSTR    68              // LDS staging row stride (floats): 64 rows + 4 pad
#define NBLK    ((N_NODES + 255) / 256)   // 196 scan blocks
#define EBLK    ((N_EDGES + 255) / 256)   // 3125 edge blocks
#define KW1_T   (51 * 128 + 128 + 128 * WP)
#define KW1_B   ((KW1_T + 255) / 256)
#define KW2_T   (51 * WP + 102)
#define KW2_B   ((KW2_T + 255) / 256)

static __device__ __forceinline__ unsigned int f2bf(float f) {
    union { float f; unsigned int u; } v; v.f = f;
    unsigned int r = v.u + 0x7FFF + ((v.u >> 16) & 1);
    return r >> 16;
}
static __device__ __forceinline__ float bflo(unsigned int u) {
    return __uint_as_float(u << 16);
}
static __device__ __forceinline__ float bfhi(unsigned int u) {
    return __uint_as_float(u & 0xFFFF0000u);
}

// ---------- histogram + weight-product kw1 (fused) ----------
__global__ void k_hist_kw1(const int* __restrict__ ei, int* __restrict__ deg,
                           const float* __restrict__ We0, const float* __restrict__ W0,
                           const float* __restrict__ be0, const float* __restrict__ W1,
                           const float* __restrict__ Wout,
                           float* __restrict__ M0, float* __restrict__ c0,
                           float* __restrict__ Wc) {
    if (blockIdx.x < EBLK) {
        int e = blockIdx.x * 256 + threadIdx.x;
        if (e < N_EDGES) atomicAdd(&deg[ei[N_EDGES + e]], 1);
        return;
    }
    int t = (blockIdx.x - EBLK) * 256 + threadIdx.x;
    if (t < 51 * 128) {
        int i = t / 128, j = t % 128;
        float a = 0.f;
        for (int k = 0; k < IN_CH; ++k) a += We0[i * IN_CH + k] * W0[k * HID + j];
        M0[t] = a;
    } else if (t < 51 * 128 + 128) {
        int j = t - 51 * 128;
        float a = 0.f;
        for (int k = 0; k < IN_CH; ++k) a += be0[k] * W0[k * HID + j];
        c0[j] = a;
    } else if (t < 51 * 128 + 128 + 128 * WP) {
        int u = t - (51 * 128 + 128);
        int i = u / WP, j = u % WP;
        float a = 0.f;
        if (j < OUT_CH)
            for (int k = 0; k < HID; ++k) a += W1[i * HID + k] * Wout[k * OUT_CH + j];
        Wc[i * WP + j] = a;
    }
}

// ---------- scan1 + weight-product kw2 (fused) ----------
__global__ void k_scan1_kw2(const int* __restrict__ deg, int* __restrict__ blksum,
                            const float* __restrict__ We1, const float* __restrict__ be1,
                            const float* __restrict__ b1, const float* __restrict__ Wout,
                            const float* __restrict__ bout, const float* __restrict__ Wc,
                            float* __restrict__ Mc, float* __restrict__ cc,
                            float* __restrict__ dd) {
    if (blockIdx.x < NBLK) {
        __shared__ int lds[256];
        int i = blockIdx.x * 256 + threadIdx.x;
        lds[threadIdx.x] = (i < N_NODES) ? deg[i] : 0;
        __syncthreads();
        for (int s = 128; s > 0; s >>= 1) {
            if (threadIdx.x < s) lds[threadIdx.x] += lds[threadIdx.x + s];
            __syncthreads();
        }
        if (threadIdx.x == 0) blksum[blockIdx.x] = lds[0];
        return;
    }
    int t = (blockIdx.x - NBLK) * 256 + threadIdx.x;
    if (t < 51 * WP) {
        int i = t / WP, j = t % WP;
        float a = 0.f;
        if (j < OUT_CH)
            for (int k = 0; k < HID; ++k) a += We1[i * HID + k] * Wc[k * WP + j];
        Mc[t] = a;
    } else if (t < 51 * WP + 51) {
        int j = t - 51 * WP;
        float a = 0.f;
        for (int k = 0; k < HID; ++k) a += be1[k] * Wc[k * WP + j];
        cc[j] = a;
    } else if (t < 51 * WP + 102) {
        int j = t - (51 * WP + 51);
        float a = 0.f;
        for (int k = 0; k < HID; ++k) a += b1[k] * Wout[k * OUT_CH + j];
        dd[j] = a + bout[j];
    }
}

// ---------- scan3 with inlined block-offset scan ----------
__global__ void k_scan3m(const int* __restrict__ deg, const int* __restrict__ blksum,
                         int* __restrict__ row_start, int* __restrict__ cursor) {
    __shared__ int lds[256];
    __shared__ int s_off;
    int tid = threadIdx.x;
    int v2 = (tid < NBLK) ? blksum[tid] : 0;
    lds[tid] = v2;
    __syncthreads();
    for (int s = 1; s < 256; s <<= 1) {
        int t = (tid >= s) ? lds[tid - s] : 0;
        __syncthreads();
        lds[tid] += t;
        __syncthreads();
    }
    if (tid == 0) s_off = (blockIdx.x == 0) ? 0 : lds[blockIdx.x - 1];
    __syncthreads();
    int boff = s_off;
    int i = blockIdx.x * 256 + tid;
    int v = (i < N_NODES) ? deg[i] : 0;
    lds[tid] = v;
    __syncthreads();
    for (int s = 1; s < 256; s <<= 1) {
        int t = (tid >= s) ? lds[tid - s] : 0;
        __syncthreads();
        lds[tid] += t;
        __syncthreads();
    }
    if (i < N_NODES) {
        int ex = boff + lds[tid] - v;
        row_start[i] = ex;
        cursor[i] = ex;
    }
    if (blockIdx.x == 0 && tid == 0) row_start[N_NODES] = N_EDGES;
}

// ---------- fill: single 4B src scatter per edge (eid no longer needed) ----------
__global__ void k_fill(const int* __restrict__ ei, int* __restrict__ cursor,
                       int* __restrict__ srcs) {
    int e = blockIdx.x * 256 + threadIdx.x;
    if (e >= N_EDGES) return;
    int src = ei[e];
    int dst = ei[N_EDGES + e];
    int pos = atomicAdd(&cursor[dst], 1);
    srcs[pos] = src;
}

// ---------- S scatter: S[dst[e]][c] += ea[e][c], linear coalesced read ----------
// edge_attr read at full HBM BW (sequential); 40.8M fp32 atomics into L2-resident S.
__global__ void k_scatter_S(const float* __restrict__ ea, const int* __restrict__ ei,
                            float* __restrict__ S) {
    const unsigned int TOT = (unsigned int)N_EDGES * EDIM;   // 40.8M elements
    unsigned int stride = gridDim.x * blockDim.x;
    for (unsigned int i = blockIdx.x * blockDim.x + threadIdx.x; i < TOT; i += stride) {
        unsigned int e = i / EDIM;            // magic-mul division by 51
        unsigned int c = i - e * EDIM;
        float v = ea[i];
        int dst = ei[N_EDGES + e];
        atomicAdd(&S[(size_t)dst * SSTR + c], v);
    }
}

// ---------- h aggregation: hacc[n] += sum_{e: dst=n} y[src[e]] ----------
__global__ void k_agg_h(const uint4* __restrict__ yb4, const int* __restrict__ srcs,
                        const int* __restrict__ row_start, float* __restrict__ hacc) {
    int n = blockIdx.x * 4 + (threadIdx.x >> 6);
    if (n >= N_NODES) return;
    int lane = threadIdx.x & 63;
    int g = lane >> 4, s = lane & 15;
    int n0 = row_start[n], n1 = row_start[n + 1];
    float acc[8];
#pragma unroll
    for (int j = 0; j < 8; ++j) acc[j] = 0.f;
    for (int base = n0; base < n1; base += 64) {
        int cnt = min(64, n1 - base);
        int s_l = (base + lane < n1) ? srcs[base + lane] : 0;
        for (int t = 0; t < cnt; t += 4) {
            int idx = t + g;
            bool ok = idx < cnt;
            int srcn = __shfl(s_l, ok ? idx : 0);
            if (ok) {
                uint4 v = yb4[(size_t)srcn * 16 + s];
                acc[0] += bflo(v.x); acc[1] += bfhi(v.x);
                acc[2] += bflo(v.y); acc[3] += bfhi(v.y);
                acc[4] += bflo(v.z); acc[5] += bfhi(v.z);
                acc[6] += bflo(v.w); acc[7] += bfhi(v.w);
            }
        }
    }
#pragma unroll
    for (int j = 0; j < 8; ++j) {
        acc[j] += __shfl_xor(acc[j], 16);
        acc[j] += __shfl_xor(acc[j], 32);
    }
    if (lane < 16) {
        float4* hp = (float4*)(hacc + (size_t)n * HID + lane * 8);
        float4 a = hp[0], b = hp[1];
        a.x += acc[0]; a.y += acc[1]; a.z += acc[2]; a.w += acc[3];
        b.x += acc[4]; b.y += acc[5]; b.z += acc[6]; b.w += acc[7];
        hp[0] = a; hp[1] = b;
    }
}

// ---------- out aggregation: out[n] += sum_{e: dst=n} w[src[e]] ----------
__global__ void k_agg_out(const uint4* __restrict__ wb4, const int* __restrict__ srcs,
                          const int* __restrict__ row_start, float* __restrict__ out) {
    int n = blockIdx.x * 4 + (threadIdx.x >> 6);
    if (n >= N_NODES) return;
    int lane = threadIdx.x & 63;
    int g = lane >> 3, s = lane & 7;
    int n0 = row_start[n], n1 = row_start[n + 1];
    float acc[8];
#pragma unroll
    for (int j = 0; j < 8; ++j) acc[j] = 0.f;
    for (int base = n0; base < n1; base += 64) {
        int cnt = min(64, n1 - base);
        int s_l = (base + lane < n1) ? srcs[base + lane] : 0;
        for (int t = 0; t < cnt; t += 8) {
            int idx = t + g;
            bool ok = idx < cnt;
            int srcn = __shfl(s_l, ok ? idx : 0);
            if (ok) {
                uint4 v = wb4[(size_t)srcn * 8 + s];
                acc[0] += bflo(v.x); acc[1] += bfhi(v.x);
                acc[2] += bflo(v.y); acc[3] += bfhi(v.y);
                acc[4] += bflo(v.z); acc[5] += bfhi(v.z);
                acc[6] += bflo(v.w); acc[7] += bfhi(v.w);
            }
        }
    }
#pragma unroll
    for (int j = 0; j < 8; ++j) {
        acc[j] += __shfl_xor(acc[j], 8);
        acc[j] += __shfl_xor(acc[j], 16);
        acc[j] += __shfl_xor(acc[j], 32);
    }
    if (lane < 8) {
#pragma unroll
        for (int j = 0; j < 8; ++j) {
            int ch = lane * 8 + j;
            if (ch < OUT_CH) out[(size_t)n * OUT_CH + ch] += acc[j];
        }
    }
}

// ---------- layer-0 tiled GEMM: y(bf16) = x@W0 ; hacc = y + S@M0 + (deg+1)*c0 + b0 ----------
__global__ __launch_bounds__(256, 4) void k_layer0(
        const float* __restrict__ x, const float* __restrict__ W0,
        const float* __restrict__ b0, const float* __restrict__ S,
        const int* __restrict__ deg, const float* __restrict__ M0,
        const float* __restrict__ c0,
        unsigned int* __restrict__ yb, float* __restrict__ hacc) {
    __shared__ float aT[64 * LSTR];   // 17,408 B
    int tid = threadIdx.x;
    int r_base = blockIdx.x * 64;
    int cg = tid & 15, rg = tid >> 4;
    int c = cg * 8, r0 = rg * 4;

    float4 accA[4], accB[4];
#pragma unroll
    for (int i = 0; i < 4; ++i) {
        accA[i] = make_float4(0.f, 0.f, 0.f, 0.f);
        accB[i] = make_float4(0.f, 0.f, 0.f, 0.f);
    }

    // ---- x phases: k = 0..150 in chunks of 64 ----
    for (int p = 0; p < 3; ++p) {
        int koff = p * 64;
        int chunk = min(64, IN_CH - koff);
        __syncthreads();
        for (int idx = tid; idx < 64 * 64; idx += 256) {
            int r = idx >> 6, kk = idx & 63;
            if (kk >= chunk) continue;
            int row = r_base + r;
            aT[kk * LSTR + r] = (row < N_NODES) ? x[(size_t)row * IN_CH + koff + kk] : 0.f;
        }
        __syncthreads();
#pragma unroll 4
        for (int kk = 0; kk < chunk; ++kk) {
            int k = koff + kk;
            float4 wv0 = *(const float4*)(W0 + k * HID + c);
            float4 wv1 = *(const float4*)(W0 + k * HID + c + 4);
            float4 a0 = *(const float4*)(&aT[kk * LSTR + r0]);
            float ar[4] = {a0.x, a0.y, a0.z, a0.w};
#pragma unroll
            for (int i = 0; i < 4; ++i) {
                accA[i].x += ar[i] * wv0.x; accA[i].y += ar[i] * wv0.y;
                accA[i].z += ar[i] * wv0.z; accA[i].w += ar[i] * wv0.w;
                accB[i].x += ar[i] * wv1.x; accB[i].y += ar[i] * wv1.y;
                accB[i].z += ar[i] * wv1.z; accB[i].w += ar[i] * wv1.w;
            }
        }
    }

    // ---- store y as bf16 ----
#pragma unroll
    for (int i = 0; i < 4; ++i) {
        int row = r_base + r0 + i;
        if (row < N_NODES) {
            uint4 pk;
            pk.x = f2bf(accA[i].x) | (f2bf(accA[i].y) << 16);
            pk.y = f2bf(accA[i].z) | (f2bf(accA[i].w) << 16);
            pk.z = f2bf(accB[i].x) | (f2bf(accB[i].y) << 16);
            pk.w = f2bf(accB[i].z) | (f2bf(accB[i].w) << 16);
            *(uint4*)(yb + (size_t)row * 64 + (c >> 1)) = pk;
        }
    }

    // ---- S phase: k = 0..50 ----
    __syncthreads();
    for (int idx = tid; idx < 64 * 64; idx += 256) {
        int r = idx >> 6, kk = idx & 63;
        if (kk >= EDIM) continue;
        int row = r_base + r;
        aT[kk * LSTR + r] = (row < N_NODES) ? S[(size_t)row * SSTR + kk] : 0.f;
    }
    __syncthreads();
#pragma unroll 4
    for (int kk = 0; kk < EDIM; ++kk) {
        float4 wv0 = *(const float4*)(M0 + kk * HID + c);
        float4 wv1 = *(const float4*)(M0 + kk * HID + c + 4);
        float4 a0 = *(const float4*)(&aT[kk * LSTR + r0]);
        float ar[4] = {a0.x, a0.y, a0.z, a0.w};
#pragma unroll
        for (int i = 0; i < 4; ++i) {
            accA[i].x += ar[i] * wv0.x; accA[i].y += ar[i] * wv0.y;
            accA[i].z += ar[i] * wv0.z; accA[i].w += ar[i] * wv0.w;
            accB[i].x += ar[i] * wv1.x; accB[i].y += ar[i] * wv1.y;
            accB[i].z += ar[i] * wv1.z; accB[i].w += ar[i] * wv1.w;
        }
    }

    // ---- epilogue: hacc = acc + (deg+1)*c0 + b0 (fp32) ----
    float4 cv0 = *(const float4*)(c0 + c);
    float4 cv1 = *(const float4*)(c0 + c + 4);
    float4 bv0 = *(const float4*)(b0 + c);
    float4 bv1 = *(const float4*)(b0 + c + 4);
#pragma unroll
    for (int i = 0; i < 4; ++i) {
        int row = r_base + r0 + i;
        if (row < N_NODES) {
            float d1 = (float)(deg[row] + 1);
            float4 vA = accA[i], vB = accB[i];
            vA.x += d1 * cv0.x + bv0.x; vA.y += d1 * cv0.y + bv0.y;
            vA.z += d1 * cv0.z + bv0.z; vA.w += d1 * cv0.w + bv0.w;
            vB.x += d1 * cv1.x + bv1.x; vB.y += d1 * cv1.y + bv1.y;
            vB.z += d1 * cv1.z + bv1.z; vB.w += d1 * cv1.w + bv1.w;
            *(float4*)(hacc + (size_t)row * HID + c) = vA;
            *(float4*)(hacc + (size_t)row * HID + c + 4) = vB;
        }
    }
}

// ---------- layer-1 tiled GEMM: w(bf16) = hacc@Wc ; out = w + S@Mc + (deg+1)*cc + dd ----------
__global__ __launch_bounds__(256, 4) void k_layer1(
        const float* __restrict__ hacc, const float* __restrict__ Wc,
        const float* __restrict__ S, const int* __restrict__ deg,
        const float* __restrict__ Mc, const float* __restrict__ cc,
        const float* __restrict__ dd,
        unsigned int* __restrict__ wb, float* __restrict__ out) {
    __shared__ float aT[64 * LSTR];
    int tid = threadIdx.x;
    int r_base = blockIdx.x * 64;
    int cg = tid & 15, rg = tid >> 4;
    int c = cg * 4, r0 = rg * 4;

    float4 acc[4];
#pragma unroll
    for (int i = 0; i < 4; ++i) acc[i] = make_float4(0.f, 0.f, 0.f, 0.f);

    // ---- h phases: k = 0..127 in chunks of 64 ----
    for (int p = 0; p < 2; ++p) {
        int koff = p * 64;
        __syncthreads();
        for (int idx = tid; idx < 64 * 64; idx += 256) {
            int r = idx >> 6, kk = idx & 63;
            int row = r_base + r;
            aT[kk * LSTR + r] = (row < N_NODES) ? hacc[(size_t)row * HID + koff + kk] : 0.f;
        }
        __syncthreads();
#pragma unroll 4
        for (int kk = 0; kk < 64; ++kk) {
            int k = koff + kk;
            float4 wv = *(const float4*)(Wc + k * WP + c);
            float4 a0 = *(const float4*)(&aT[kk * LSTR + r0]);
            float ar[4] = {a0.x, a0.y, a0.z, a0.w};
#pragma unroll
            for (int i = 0; i < 4; ++i) {
                acc[i].x += ar[i] * wv.x; acc[i].y += ar[i] * wv.y;
                acc[i].z += ar[i] * wv.z; acc[i].w += ar[i] * wv.w;
            }
        }
    }

    // ---- store w as bf16 (padded 64) ----
#pragma unroll
    for (int i = 0; i < 4; ++i) {
        int row = r_base + r0 + i;
        if (row < N_NODES) {
            uint2 pk;
            pk.x = f2bf(acc[i].x) | (f2bf(acc[i].y) << 16);
            pk.y = f2bf(acc[i].z) | (f2bf(acc[i].w) << 16);
            *(uint2*)(wb + (size_t)row * 32 + (c >> 1)) = pk;
        }
    }

    // ---- S phase ----
    __syncthreads();
    for (int idx = tid; idx < 64 * 64; idx += 256) {
        int r = idx >> 6, kk = idx & 63;
        if (kk >= EDIM) continue;
        int row = r_base + r;
        aT[kk * LSTR + r] = (row < N_NODES) ? S[(size_t)row * SSTR + kk] : 0.f;
    }
    __syncthreads();
#pragma unroll 4
    for (int kk = 0; kk < EDIM; ++kk) {
        float4 wv = *(const float4*)(Mc + kk * WP + c);
        float4 a0 = *(const float4*)(&aT[kk * LSTR + r0]);
        float ar[4] = {a0.x, a0.y, a0.z, a0.w};
#pragma unroll
        for (int i = 0; i < 4; ++i) {
            acc[i].x += ar[i] * wv.x; acc[i].y += ar[i] * wv.y;
            acc[i].z += ar[i] * wv.z; acc[i].w += ar[i] * wv.w;
        }
    }

    // ---- epilogue: out = acc + (deg+1)*cc + dd, cols < 51 ----
    if (c < OUT_CH) {
        float cv[4], dv[4];
#pragma unroll
        for (int j = 0; j < 4; ++j) {
            int col = c + j;
            cv[j] = (col < OUT_CH) ? cc[col] : 0.f;
            dv[j] = (col < OUT_CH) ? dd[col] : 0.f;
        }
#pragma unroll
        for (int i = 0; i < 4; ++i) {
            int row = r_base + r0 + i;
            if (row < N_NODES) {
                float d1 = (float)(deg[row] + 1);
                const float* ap = (const float*)&acc[i];
#pragma unroll
                for (int j = 0; j < 4; ++j) {
                    int col = c + j;
                    if (col < OUT_CH)
                        out[(size_t)row * OUT_CH + col] = ap[j] + d1 * cv[j] + dv[j];
                }
            }
        }
    }
}

extern "C" void kernel_launch(void* const* d_in, const int* in_sizes, int n_in,
                              void* d_out, int out_size, void* d_ws, size_t ws_size,
                              hipStream_t stream) {
    const float* x    = (const float*)d_in[0];
    const float* ea   = (const float*)d_in[1];
    const float* We0  = (const float*)d_in[2];
    const float* be0  = (const float*)d_in[3];
    const float* W0   = (const float*)d_in[4];
    const float* b0   = (const float*)d_in[5];
    const float* We1  = (const float*)d_in[6];
    const float* be1  = (const float*)d_in[7];
    const float* W1   = (const float*)d_in[8];
    const float* b1   = (const float*)d_in[9];
    const float* Wout = (const float*)d_in[10];
    const float* bout = (const float*)d_in[11];
    const int*   ei   = (const int*)d_in[12];
    float* out = (float*)d_out;

    char* p = (char*)d_ws;
    auto alloc = [&](size_t bytes) {
        char* r = p;
        p += (bytes + 255) & ~(size_t)255;
        return r;
    };
    // deg and S adjacent: one memset zeroes both
    int*   deg       = (int*)  alloc((size_t)N_NODES * 4);
    float* S         = (float*)alloc((size_t)N_NODES * SSTR * 4);    // 10.4 MB
    size_t zspan     = (size_t)((char*)(S + (size_t)N_NODES * SSTR) - (char*)deg);
    int*   row_start = (int*)  alloc((size_t)(N_NODES + 1) * 4);
    int*   cursor    = (int*)  alloc((size_t)N_NODES * 4);
    int*   blksum    = (int*)  alloc((size_t)NBLK * 4);
    int*   srcs      = (int*)  alloc((size_t)N_EDGES * 4);           // 3.2 MB
    unsigned int* yb = (unsigned int*)alloc((size_t)N_NODES * 64 * 4);  // y bf16: 12.8 MB
    float* hacc      = (float*)alloc((size_t)N_NODES * HID * 4);     // 25.6 MB
    unsigned int* wb = (unsigned int*)alloc((size_t)N_NODES * 32 * 4);  // w bf16: 6.4 MB
    float* M0        = (float*)alloc(51 * 128 * 4);
    float* c0        = (float*)alloc(128 * 4);
    float* Wc        = (float*)alloc(128 * WP * 4);
    float* Mc        = (float*)alloc(51 * WP * 4);
    float* cc        = (float*)alloc(51 * 4);
    float* dd        = (float*)alloc(51 * 4);

    hipMemsetAsync(deg, 0, zspan, stream);   // zero deg + S in one call

    k_hist_kw1<<<EBLK + KW1_B, 256, 0, stream>>>(ei, deg, We0, W0, be0, W1, Wout, M0, c0, Wc);
    k_scan1_kw2<<<NBLK + KW2_B, 256, 0, stream>>>(deg, blksum, We1, be1, b1, Wout, bout,
                                                  Wc, Mc, cc, dd);
    k_scan3m<<<NBLK, 256, 0, stream>>>(deg, blksum, row_start, cursor);
    k_fill<<<EBLK, 256, 0, stream>>>(ei, cursor, srcs);

    // S via linear-read atomic scatter (replaces permuted-read gather)
    k_scatter_S<<<4096, 256, 0, stream>>>(ea, ei, S);

    // layer 0
    k_layer0<<<(N_NODES + 63) / 64, 256, 0, stream>>>(x, W0, b0, S, deg, M0, c0, yb, hacc);
    k_agg_h<<<(N_NODES + 3) / 4, 256, 0, stream>>>((const uint4*)yb, srcs, row_start, hacc);

    // layer 1 + output projection
    k_layer1<<<(N_NODES + 63) / 64, 256, 0, stream>>>(hacc, Wc, S, deg, Mc, cc, dd, wb, out);
    k_agg_out<<<(N_NODES + 3) / 4, 256, 0, stream>>>((const uint4*)wb, srcs, row_start, out);
}

// Round 6
// 666.936 us; speedup vs baseline: 1.0608x; 1.0608x over previous
//
#include <hip/hip_runtime.h>

#define N_NODES 50000
#define N_EDGES 800000
#define IN_CH   151
#define HID     128
#define OUT_CH  51
#define EDIM    51
#define SSTR    52              // padded S row stride (floats): 51 + 1 pad -> 208B rows
#define WP      64              // padded minor dim for Wc / Mc
#define LSTR    68              // LDS staging row stride (floats): 64 rows + 4 pad
#define YPQ     ((size_t)N_NODES * 16)    // uints per y plane (32ch bf16 = 64B/row)
#define WPQ     ((size_t)N_NODES * 16)    // uints per w plane
#define NBLK    ((N_NODES + 255) / 256)   // 196 scan blocks
#define EBLK    ((N_EDGES + 255) / 256)   // 3125 edge blocks
#define KW1_T   (51 * 128 + 128 + 128 * WP)
#define KW1_B   ((KW1_T + 255) / 256)
#define KW2_T   (51 * WP + 102)
#define KW2_B   ((KW2_T + 255) / 256)

static __device__ __forceinline__ unsigned int f2bf(float f) {
    union { float f; unsigned int u; } v; v.f = f;
    unsigned int r = v.u + 0x7FFF + ((v.u >> 16) & 1);
    return r >> 16;
}
static __device__ __forceinline__ float bflo(unsigned int u) {
    return __uint_as_float(u << 16);
}
static __device__ __forceinline__ float bfhi(unsigned int u) {
    return __uint_as_float(u & 0xFFFF0000u);
}

// ---------- histogram + weight-product kw1 (fused) ----------
__global__ void k_hist_kw1(const int* __restrict__ ei, int* __restrict__ deg,
                           const float* __restrict__ We0, const float* __restrict__ W0,
                           const float* __restrict__ be0, const float* __restrict__ W1,
                           const float* __restrict__ Wout,
                           float* __restrict__ M0, float* __restrict__ c0,
                           float* __restrict__ Wc) {
    if (blockIdx.x < EBLK) {
        int e = blockIdx.x * 256 + threadIdx.x;
        if (e < N_EDGES) atomicAdd(&deg[ei[N_EDGES + e]], 1);
        return;
    }
    int t = (blockIdx.x - EBLK) * 256 + threadIdx.x;
    if (t < 51 * 128) {
        int i = t / 128, j = t % 128;
        float a = 0.f;
        for (int k = 0; k < IN_CH; ++k) a += We0[i * IN_CH + k] * W0[k * HID + j];
        M0[t] = a;
    } else if (t < 51 * 128 + 128) {
        int j = t - 51 * 128;
        float a = 0.f;
        for (int k = 0; k < IN_CH; ++k) a += be0[k] * W0[k * HID + j];
        c0[j] = a;
    } else if (t < 51 * 128 + 128 + 128 * WP) {
        int u = t - (51 * 128 + 128);
        int i = u / WP, j = u % WP;
        float a = 0.f;
        if (j < OUT_CH)
            for (int k = 0; k < HID; ++k) a += W1[i * HID + k] * Wout[k * OUT_CH + j];
        Wc[i * WP + j] = a;
    }
}

// ---------- scan1 + weight-product kw2 (fused) ----------
__global__ void k_scan1_kw2(const int* __restrict__ deg, int* __restrict__ blksum,
                            const float* __restrict__ We1, const float* __restrict__ be1,
                            const float* __restrict__ b1, const float* __restrict__ Wout,
                            const float* __restrict__ bout, const float* __restrict__ Wc,
                            float* __restrict__ Mc, float* __restrict__ cc,
                            float* __restrict__ dd) {
    if (blockIdx.x < NBLK) {
        __shared__ int lds[256];
        int i = blockIdx.x * 256 + threadIdx.x;
        lds[threadIdx.x] = (i < N_NODES) ? deg[i] : 0;
        __syncthreads();
        for (int s = 128; s > 0; s >>= 1) {
            if (threadIdx.x < s) lds[threadIdx.x] += lds[threadIdx.x + s];
            __syncthreads();
        }
        if (threadIdx.x == 0) blksum[blockIdx.x] = lds[0];
        return;
    }
    int t = (blockIdx.x - NBLK) * 256 + threadIdx.x;
    if (t < 51 * WP) {
        int i = t / WP, j = t % WP;
        float a = 0.f;
        if (j < OUT_CH)
            for (int k = 0; k < HID; ++k) a += We1[i * HID + k] * Wc[k * WP + j];
        Mc[t] = a;
    } else if (t < 51 * WP + 51) {
        int j = t - 51 * WP;
        float a = 0.f;
        for (int k = 0; k < HID; ++k) a += be1[k] * Wc[k * WP + j];
        cc[j] = a;
    } else if (t < 51 * WP + 102) {
        int j = t - (51 * WP + 51);
        float a = 0.f;
        for (int k = 0; k < HID; ++k) a += b1[k] * Wout[k * OUT_CH + j];
        dd[j] = a + bout[j];
    }
}

// ---------- scan3 with inlined block-offset scan ----------
__global__ void k_scan3m(const int* __restrict__ deg, const int* __restrict__ blksum,
                         int* __restrict__ row_start, int* __restrict__ cursor) {
    __shared__ int lds[256];
    __shared__ int s_off;
    int tid = threadIdx.x;
    int v2 = (tid < NBLK) ? blksum[tid] : 0;
    lds[tid] = v2;
    __syncthreads();
    for (int s = 1; s < 256; s <<= 1) {
        int t = (tid >= s) ? lds[tid - s] : 0;
        __syncthreads();
        lds[tid] += t;
        __syncthreads();
    }
    if (tid == 0) s_off = (blockIdx.x == 0) ? 0 : lds[blockIdx.x - 1];
    __syncthreads();
    int boff = s_off;
    int i = blockIdx.x * 256 + tid;
    int v = (i < N_NODES) ? deg[i] : 0;
    lds[tid] = v;
    __syncthreads();
    for (int s = 1; s < 256; s <<= 1) {
        int t = (tid >= s) ? lds[tid - s] : 0;
        __syncthreads();
        lds[tid] += t;
        __syncthreads();
    }
    if (i < N_NODES) {
        int ex = boff + lds[tid] - v;
        row_start[i] = ex;
        cursor[i] = ex;
    }
    if (blockIdx.x == 0 && tid == 0) row_start[N_NODES] = N_EDGES;
}

// ---------- fill: single int2{src, eid} 8B scatter per edge ----------
__global__ void k_fill(const int* __restrict__ ei, int* __restrict__ cursor,
                       int2* __restrict__ pairs) {
    int e = blockIdx.x * 256 + threadIdx.x;
    if (e >= N_EDGES) return;
    int src = ei[e];
    int dst = ei[N_EDGES + e];
    int pos = atomicAdd(&cursor[dst], 1);
    pairs[pos] = make_int2(src, e);
}

// ---------- S aggregation: S[n] = sum_{e: dst=n} edge_attr[e] (permuted gather) ----------
__global__ void k_agg_S(const float* __restrict__ ea, const int2* __restrict__ pairs,
                        const int* __restrict__ row_start, float* __restrict__ S) {
    int n = blockIdx.x * 4 + (threadIdx.x >> 6);
    if (n >= N_NODES) return;
    int lane = threadIdx.x & 63;
    int g = lane >> 4, sub = lane & 15;
    int n0 = row_start[n], n1 = row_start[n + 1];
    float4 acc = make_float4(0.f, 0.f, 0.f, 0.f);
    for (int base = n0; base < n1; base += 64) {
        int cnt = min(64, n1 - base);
        int eid_l = (base + lane < n1) ? pairs[base + lane].y : 0;
        for (int t = 0; t < cnt; t += 4) {
            int idx = t + g;
            bool ok = idx < cnt;
            int e = __shfl(eid_l, ok ? idx : 0);
            if (ok && sub < 13) {
                float4 v = *(const float4*)(ea + (size_t)e * EDIM + sub * 4);
                if (sub == 12) v.w = 0.f;   // ch 51 belongs to next row
                acc.x += v.x; acc.y += v.y; acc.z += v.z; acc.w += v.w;
            }
        }
    }
    acc.x += __shfl_xor(acc.x, 16); acc.y += __shfl_xor(acc.y, 16);
    acc.z += __shfl_xor(acc.z, 16); acc.w += __shfl_xor(acc.w, 16);
    acc.x += __shfl_xor(acc.x, 32); acc.y += __shfl_xor(acc.y, 32);
    acc.z += __shfl_xor(acc.z, 32); acc.w += __shfl_xor(acc.w, 32);
    if (lane < 13)
        *(float4*)(S + (size_t)n * SSTR + lane * 4) = acc;
}

// ---------- h aggregation, one 32-channel plane per launch ----------
// Plane = 3.2 MB (< 4 MB per-XCD L2): 16x reuse hits L2 instead of thrashing HBM.
// 4 lanes/edge (64B row), 16 edges per wave-load; reduce shfl_xor(4,8,16,32).
__global__ void k_agg_h_p(const uint4* __restrict__ yq, const int2* __restrict__ pairs,
                          const int* __restrict__ row_start, float* __restrict__ hacc,
                          int coff) {
    int n = blockIdx.x * 4 + (threadIdx.x >> 6);
    if (n >= N_NODES) return;
    int lane = threadIdx.x & 63;
    int g = lane >> 2, s = lane & 3;
    int n0 = row_start[n], n1 = row_start[n + 1];
    float acc[8];
#pragma unroll
    for (int j = 0; j < 8; ++j) acc[j] = 0.f;
    for (int base = n0; base < n1; base += 64) {
        int cnt = min(64, n1 - base);
        int s_l = (base + lane < n1) ? pairs[base + lane].x : 0;
        for (int t = 0; t < cnt; t += 16) {
            int idx = t + g;
            bool ok = idx < cnt;
            int srcn = __shfl(s_l, ok ? idx : 0);
            if (ok) {
                uint4 v = yq[(size_t)srcn * 4 + s];
                acc[0] += bflo(v.x); acc[1] += bfhi(v.x);
                acc[2] += bflo(v.y); acc[3] += bfhi(v.y);
                acc[4] += bflo(v.z); acc[5] += bfhi(v.z);
                acc[6] += bflo(v.w); acc[7] += bfhi(v.w);
            }
        }
    }
#pragma unroll
    for (int j = 0; j < 8; ++j) {
        acc[j] += __shfl_xor(acc[j], 4);
        acc[j] += __shfl_xor(acc[j], 8);
        acc[j] += __shfl_xor(acc[j], 16);
        acc[j] += __shfl_xor(acc[j], 32);
    }
    if (lane < 4) {
        float4* hp = (float4*)(hacc + (size_t)n * HID + coff + lane * 8);
        float4 a = hp[0], b = hp[1];
        a.x += acc[0]; a.y += acc[1]; a.z += acc[2]; a.w += acc[3];
        b.x += acc[4]; b.y += acc[5]; b.z += acc[6]; b.w += acc[7];
        hp[0] = a; hp[1] = b;
    }
}

// ---------- out aggregation, one 32-channel plane per launch ----------
__global__ void k_agg_out_p(const uint4* __restrict__ wq, const int2* __restrict__ pairs,
                            const int* __restrict__ row_start, float* __restrict__ out,
                            int coff) {
    int n = blockIdx.x * 4 + (threadIdx.x >> 6);
    if (n >= N_NODES) return;
    int lane = threadIdx.x & 63;
    int g = lane >> 2, s = lane & 3;
    int n0 = row_start[n], n1 = row_start[n + 1];
    float acc[8];
#pragma unroll
    for (int j = 0; j < 8; ++j) acc[j] = 0.f;
    for (int base = n0; base < n1; base += 64) {
        int cnt = min(64, n1 - base);
        int s_l = (base + lane < n1) ? pairs[base + lane].x : 0;
        for (int t = 0; t < cnt; t += 16) {
            int idx = t + g;
            bool ok = idx < cnt;
            int srcn = __shfl(s_l, ok ? idx : 0);
            if (ok) {
                uint4 v = wq[(size_t)srcn * 4 + s];
                acc[0] += bflo(v.x); acc[1] += bfhi(v.x);
                acc[2] += bflo(v.y); acc[3] += bfhi(v.y);
                acc[4] += bflo(v.z); acc[5] += bfhi(v.z);
                acc[6] += bflo(v.w); acc[7] += bfhi(v.w);
            }
        }
    }
#pragma unroll
    for (int j = 0; j < 8; ++j) {
        acc[j] += __shfl_xor(acc[j], 4);
        acc[j] += __shfl_xor(acc[j], 8);
        acc[j] += __shfl_xor(acc[j], 16);
        acc[j] += __shfl_xor(acc[j], 32);
    }
    if (lane < 4) {
#pragma unroll
        for (int j = 0; j < 8; ++j) {
            int ch = coff + lane * 8 + j;
            if (ch < OUT_CH) out[(size_t)n * OUT_CH + ch] += acc[j];
        }
    }
}

// ---------- layer-0 tiled GEMM: y(bf16, 4 planes) = x@W0 ; hacc = y + S@M0 + (deg+1)*c0 + b0 ----------
__global__ __launch_bounds__(256, 4) void k_layer0(
        const float* __restrict__ x, const float* __restrict__ W0,
        const float* __restrict__ b0, const float* __restrict__ S,
        const int* __restrict__ deg, const float* __restrict__ M0,
        const float* __restrict__ c0,
        unsigned int* __restrict__ yb, float* __restrict__ hacc) {
    __shared__ float aT[64 * LSTR];   // 17,408 B
    int tid = threadIdx.x;
    int r_base = blockIdx.x * 64;
    int cg = tid & 15, rg = tid >> 4;
    int c = cg * 8, r0 = rg * 4;

    float4 accA[4], accB[4];
#pragma unroll
    for (int i = 0; i < 4; ++i) {
        accA[i] = make_float4(0.f, 0.f, 0.f, 0.f);
        accB[i] = make_float4(0.f, 0.f, 0.f, 0.f);
    }

    // ---- x phases: k = 0..150 in chunks of 64 ----
    for (int p = 0; p < 3; ++p) {
        int koff = p * 64;
        int chunk = min(64, IN_CH - koff);
        __syncthreads();
        for (int idx = tid; idx < 64 * 64; idx += 256) {
            int r = idx >> 6, kk = idx & 63;
            if (kk >= chunk) continue;
            int row = r_base + r;
            aT[kk * LSTR + r] = (row < N_NODES) ? x[(size_t)row * IN_CH + koff + kk] : 0.f;
        }
        __syncthreads();
#pragma unroll 4
        for (int kk = 0; kk < chunk; ++kk) {
            int k = koff + kk;
            float4 wv0 = *(const float4*)(W0 + k * HID + c);
            float4 wv1 = *(const float4*)(W0 + k * HID + c + 4);
            float4 a0 = *(const float4*)(&aT[kk * LSTR + r0]);
            float ar[4] = {a0.x, a0.y, a0.z, a0.w};
#pragma unroll
            for (int i = 0; i < 4; ++i) {
                accA[i].x += ar[i] * wv0.x; accA[i].y += ar[i] * wv0.y;
                accA[i].z += ar[i] * wv0.z; accA[i].w += ar[i] * wv0.w;
                accB[i].x += ar[i] * wv1.x; accB[i].y += ar[i] * wv1.y;
                accB[i].z += ar[i] * wv1.z; accB[i].w += ar[i] * wv1.w;
            }
        }
    }

    // ---- store y as bf16 into plane (c>>5), offset (c&31)*2B ----
    {
        int q = c >> 5;
        int uoff = (c & 31) >> 1;
        unsigned int* yp = yb + (size_t)q * YPQ;
#pragma unroll
        for (int i = 0; i < 4; ++i) {
            int row = r_base + r0 + i;
            if (row < N_NODES) {
                uint4 pk;
                pk.x = f2bf(accA[i].x) | (f2bf(accA[i].y) << 16);
                pk.y = f2bf(accA[i].z) | (f2bf(accA[i].w) << 16);
                pk.z = f2bf(accB[i].x) | (f2bf(accB[i].y) << 16);
                pk.w = f2bf(accB[i].z) | (f2bf(accB[i].w) << 16);
                *(uint4*)(yp + (size_t)row * 16 + uoff) = pk;
            }
        }
    }

    // ---- S phase: k = 0..50 ----
    __syncthreads();
    for (int idx = tid; idx < 64 * 64; idx += 256) {
        int r = idx >> 6, kk = idx & 63;
        if (kk >= EDIM) continue;
        int row = r_base + r;
        aT[kk * LSTR + r] = (row < N_NODES) ? S[(size_t)row * SSTR + kk] : 0.f;
    }
    __syncthreads();
#pragma unroll 4
    for (int kk = 0; kk < EDIM; ++kk) {
        float4 wv0 = *(const float4*)(M0 + kk * HID + c);
        float4 wv1 = *(const float4*)(M0 + kk * HID + c + 4);
        float4 a0 = *(const float4*)(&aT[kk * LSTR + r0]);
        float ar[4] = {a0.x, a0.y, a0.z, a0.w};
#pragma unroll
        for (int i = 0; i < 4; ++i) {
            accA[i].x += ar[i] * wv0.x; accA[i].y += ar[i] * wv0.y;
            accA[i].z += ar[i] * wv0.z; accA[i].w += ar[i] * wv0.w;
            accB[i].x += ar[i] * wv1.x; accB[i].y += ar[i] * wv1.y;
            accB[i].z += ar[i] * wv1.z; accB[i].w += ar[i] * wv1.w;
        }
    }

    // ---- epilogue: hacc = acc + (deg+1)*c0 + b0 (fp32) ----
    float4 cv0 = *(const float4*)(c0 + c);
    float4 cv1 = *(const float4*)(c0 + c + 4);
    float4 bv0 = *(const float4*)(b0 + c);
    float4 bv1 = *(const float4*)(b0 + c + 4);
#pragma unroll
    for (int i = 0; i < 4; ++i) {
        int row = r_base + r0 + i;
        if (row < N_NODES) {
            float d1 = (float)(deg[row] + 1);
            float4 vA = accA[i], vB = accB[i];
            vA.x += d1 * cv0.x + bv0.x; vA.y += d1 * cv0.y + bv0.y;
            vA.z += d1 * cv0.z + bv0.z; vA.w += d1 * cv0.w + bv0.w;
            vB.x += d1 * cv1.x + bv1.x; vB.y += d1 * cv1.y + bv1.y;
            vB.z += d1 * cv1.z + bv1.z; vB.w += d1 * cv1.w + bv1.w;
            *(float4*)(hacc + (size_t)row * HID + c) = vA;
            *(float4*)(hacc + (size_t)row * HID + c + 4) = vB;
        }
    }
}

// ---------- layer-1 tiled GEMM: w(bf16, 2 planes) = hacc@Wc ; out = w + S@Mc + (deg+1)*cc + dd ----------
__global__ __launch_bounds__(256, 4) void k_layer1(
        const float* __restrict__ hacc, const float* __restrict__ Wc,
        const float* __restrict__ S, const int* __restrict__ deg,
        const float* __restrict__ Mc, const float* __restrict__ cc,
        const float* __restrict__ dd,
        unsigned int* __restrict__ wb, float* __restrict__ out) {
    __shared__ float aT[64 * LSTR];
    int tid = threadIdx.x;
    int r_base = blockIdx.x * 64;
    int cg = tid & 15, rg = tid >> 4;
    int c = cg * 4, r0 = rg * 4;

    float4 acc[4];
#pragma unroll
    for (int i = 0; i < 4; ++i) acc[i] = make_float4(0.f, 0.f, 0.f, 0.f);

    // ---- h phases: k = 0..127 in chunks of 64 ----
    for (int p = 0; p < 2; ++p) {
        int koff = p * 64;
        __syncthreads();
        for (int idx = tid; idx < 64 * 64; idx += 256) {
            int r = idx >> 6, kk = idx & 63;
            int row = r_base + r;
            aT[kk * LSTR + r] = (row < N_NODES) ? hacc[(size_t)row * HID + koff + kk] : 0.f;
        }
        __syncthreads();
#pragma unroll 4
        for (int kk = 0; kk < 64; ++kk) {
            int k = koff + kk;
            float4 wv = *(const float4*)(Wc + k * WP + c);
            float4 a0 = *(const float4*)(&aT[kk * LSTR + r0]);
            float ar[4] = {a0.x, a0.y, a0.z, a0.w};
#pragma unroll
            for (int i = 0; i < 4; ++i) {
                acc[i].x += ar[i] * wv.x; acc[i].y += ar[i] * wv.y;
                acc[i].z += ar[i] * wv.z; acc[i].w += ar[i] * wv.w;
            }
        }
    }

    // ---- store w as bf16 into plane (c>>5) ----
    {
        int q = c >> 5;
        int uoff = (c & 31) >> 1;
        unsigned int* wp = wb + (size_t)q * WPQ;
#pragma unroll
        for (int i = 0; i < 4; ++i) {
            int row = r_base + r0 + i;
            if (row < N_NODES) {
                uint2 pk;
                pk.x = f2bf(acc[i].x) | (f2bf(acc[i].y) << 16);
                pk.y = f2bf(acc[i].z) | (f2bf(acc[i].w) << 16);
                *(uint2*)(wp + (size_t)row * 16 + uoff) = pk;
            }
        }
    }

    // ---- S phase ----
    __syncthreads();
    for (int idx = tid; idx < 64 * 64; idx += 256) {
        int r = idx >> 6, kk = idx & 63;
        if (kk >= EDIM) continue;
        int row = r_base + r;
        aT[kk * LSTR + r] = (row < N_NODES) ? S[(size_t)row * SSTR + kk] : 0.f;
    }
    __syncthreads();
#pragma unroll 4
    for (int kk = 0; kk < EDIM; ++kk) {
        float4 wv = *(const float4*)(Mc + kk * WP + c);
        float4 a0 = *(const float4*)(&aT[kk * LSTR + r0]);
        float ar[4] = {a0.x, a0.y, a0.z, a0.w};
#pragma unroll
        for (int i = 0; i < 4; ++i) {
            acc[i].x += ar[i] * wv.x; acc[i].y += ar[i] * wv.y;
            acc[i].z += ar[i] * wv.z; acc[i].w += ar[i] * wv.w;
        }
    }

    // ---- epilogue: out = acc + (deg+1)*cc + dd, cols < 51 ----
    if (c < OUT_CH) {
        float cv[4], dv[4];
#pragma unroll
        for (int j = 0; j < 4; ++j) {
            int col = c + j;
            cv[j] = (col < OUT_CH) ? cc[col] : 0.f;
            dv[j] = (col < OUT_CH) ? dd[col] : 0.f;
        }
#pragma unroll
        for (int i = 0; i < 4; ++i) {
            int row = r_base + r0 + i;
            if (row < N_NODES) {
                float d1 = (float)(deg[row] + 1);
                const float* ap = (const float*)&acc[i];
#pragma unroll
                for (int j = 0; j < 4; ++j) {
                    int col = c + j;
                    if (col < OUT_CH)
                        out[(size_t)row * OUT_CH + col] = ap[j] + d1 * cv[j] + dv[j];
                }
            }
        }
    }
}

extern "C" void kernel_launch(void* const* d_in, const int* in_sizes, int n_in,
                              void* d_out, int out_size, void* d_ws, size_t ws_size,
                              hipStream_t stream) {
    const float* x    = (const float*)d_in[0];
    const float* ea   = (const float*)d_in[1];
    const float* We0  = (const float*)d_in[2];
    const float* be0  = (const float*)d_in[3];
    const float* W0   = (const float*)d_in[4];
    const float* b0   = (const float*)d_in[5];
    const float* We1  = (const float*)d_in[6];
    const float* be1  = (const float*)d_in[7];
    const float* W1   = (const float*)d_in[8];
    const float* b1   = (const float*)d_in[9];
    const float* Wout = (const float*)d_in[10];
    const float* bout = (const float*)d_in[11];
    const int*   ei   = (const int*)d_in[12];
    float* out = (float*)d_out;

    char* p = (char*)d_ws;
    auto alloc = [&](size_t bytes) {
        char* r = p;
        p += (bytes + 255) & ~(size_t)255;
        return r;
    };
    float* S         = (float*)alloc((size_t)N_NODES * SSTR * 4);    // 10.4 MB
    int*   deg       = (int*)  alloc((size_t)N_NODES * 4);
    int*   row_start = (int*)  alloc((size_t)(N_NODES + 1) * 4);
    int*   cursor    = (int*)  alloc((size_t)N_NODES * 4);
    int*   blksum    = (int*)  alloc((size_t)NBLK * 4);
    int2*  pairs     = (int2*) alloc((size_t)N_EDGES * 8);           // 6.4 MB {src, eid}
    unsigned int* yb = (unsigned int*)alloc((size_t)N_NODES * 64 * 4);  // y bf16: 4 planes x 3.2 MB
    float* hacc      = (float*)alloc((size_t)N_NODES * HID * 4);     // 25.6 MB
    unsigned int* wb = (unsigned int*)alloc((size_t)N_NODES * 32 * 4);  // w bf16: 2 planes x 3.2 MB
    float* M0        = (float*)alloc(51 * 128 * 4);
    float* c0        = (float*)alloc(128 * 4);
    float* Wc        = (float*)alloc(128 * WP * 4);
    float* Mc        = (float*)alloc(51 * WP * 4);
    float* cc        = (float*)alloc(51 * 4);
    float* dd        = (float*)alloc(51 * 4);

    hipMemsetAsync(deg, 0, (size_t)N_NODES * 4, stream);

    k_hist_kw1<<<EBLK + KW1_B, 256, 0, stream>>>(ei, deg, We0, W0, be0, W1, Wout, M0, c0, Wc);
    k_scan1_kw2<<<NBLK + KW2_B, 256, 0, stream>>>(deg, blksum, We1, be1, b1, Wout, bout,
                                                  Wc, Mc, cc, dd);
    k_scan3m<<<NBLK, 256, 0, stream>>>(deg, blksum, row_start, cursor);
    k_fill<<<EBLK, 256, 0, stream>>>(ei, cursor, pairs);

    // S aggregation (permuted gather, Round-3 version)
    k_agg_S<<<(N_NODES + 3) / 4, 256, 0, stream>>>(ea, pairs, row_start, S);

    // layer 0
    k_layer0<<<(N_NODES + 63) / 64, 256, 0, stream>>>(x, W0, b0, S, deg, M0, c0, yb, hacc);

    // h aggregation: 4 sequential 32-channel plane passes (each plane 3.2 MB, L2-resident)
    for (int q = 0; q < 4; ++q)
        k_agg_h_p<<<(N_NODES + 3) / 4, 256, 0, stream>>>(
            (const uint4*)(yb + (size_t)q * YPQ), pairs, row_start, hacc, q * 32);

    // layer 1 + output projection
    k_layer1<<<(N_NODES + 63) / 64, 256, 0, stream>>>(hacc, Wc, S, deg, Mc, cc, dd, wb, out);

    // out aggregation: 2 plane passes
    for (int q = 0; q < 2; ++q)
        k_agg_out_p<<<(N_NODES + 3) / 4, 256, 0, stream>>>(
            (const uint4*)(wb + (size_t)q * WPQ), pairs, row_start, out, q * 32);
}

// Round 7
// 579.259 us; speedup vs baseline: 1.2214x; 1.1514x over previous
//
#include <hip/hip_runtime.h>

#define N_NODES 50000
#define N_EDGES 800000
#define IN_CH   151
#define HID     128
#define OUT_CH  51
#define EDIM    51
#define SSTR    52              // padded S row stride (floats): 51 + 1 pad -> 208B rows
#define WP      64              // padded minor dim for Wc / Mc
#define LSTR    68              // LDS staging row stride (floats): 64 rows + 4 pad
#define NBLK    ((N_NODES + 255) / 256)   // 196 scan blocks
#define EBLK    ((N_EDGES + 255) / 256)   // 3125 edge blocks
#define KW1_T   (51 * 128 + 128 + 128 * WP)
#define KW1_B   ((KW1_T + 255) / 256)
#define KW2_T   (51 * WP + 102)
#define KW2_B   ((KW2_T + 255) / 256)

static __device__ __forceinline__ unsigned int f2bf(float f) {
    union { float f; unsigned int u; } v; v.f = f;
    unsigned int r = v.u + 0x7FFF + ((v.u >> 16) & 1);
    return r >> 16;
}
static __device__ __forceinline__ float bflo(unsigned int u) {
    return __uint_as_float(u << 16);
}
static __device__ __forceinline__ float bfhi(unsigned int u) {
    return __uint_as_float(u & 0xFFFF0000u);
}

// ---------- histogram + weight-product kw1 (fused) ----------
__global__ void k_hist_kw1(const int* __restrict__ ei, int* __restrict__ deg,
                           const float* __restrict__ We0, const float* __restrict__ W0,
                           const float* __restrict__ be0, const float* __restrict__ W1,
                           const float* __restrict__ Wout,
                           float* __restrict__ M0, float* __restrict__ c0,
                           float* __restrict__ Wc) {
    if (blockIdx.x < EBLK) {
        int e = blockIdx.x * 256 + threadIdx.x;
        if (e < N_EDGES) atomicAdd(&deg[ei[N_EDGES + e]], 1);
        return;
    }
    int t = (blockIdx.x - EBLK) * 256 + threadIdx.x;
    if (t < 51 * 128) {
        int i = t / 128, j = t % 128;
        float a = 0.f;
        for (int k = 0; k < IN_CH; ++k) a += We0[i * IN_CH + k] * W0[k * HID + j];
        M0[t] = a;
    } else if (t < 51 * 128 + 128) {
        int j = t - 51 * 128;
        float a = 0.f;
        for (int k = 0; k < IN_CH; ++k) a += be0[k] * W0[k * HID + j];
        c0[j] = a;
    } else if (t < 51 * 128 + 128 + 128 * WP) {
        int u = t - (51 * 128 + 128);
        int i = u / WP, j = u % WP;
        float a = 0.f;
        if (j < OUT_CH)
            for (int k = 0; k < HID; ++k) a += W1[i * HID + k] * Wout[k * OUT_CH + j];
        Wc[i * WP + j] = a;
    }
}

// ---------- scan1 + weight-product kw2 (fused) ----------
__global__ void k_scan1_kw2(const int* __restrict__ deg, int* __restrict__ blksum,
                            const float* __restrict__ We1, const float* __restrict__ be1,
                            const float* __restrict__ b1, const float* __restrict__ Wout,
                            const float* __restrict__ bout, const float* __restrict__ Wc,
                            float* __restrict__ Mc, float* __restrict__ cc,
                            float* __restrict__ dd) {
    if (blockIdx.x < NBLK) {
        __shared__ int lds[256];
        int i = blockIdx.x * 256 + threadIdx.x;
        lds[threadIdx.x] = (i < N_NODES) ? deg[i] : 0;
        __syncthreads();
        for (int s = 128; s > 0; s >>= 1) {
            if (threadIdx.x < s) lds[threadIdx.x] += lds[threadIdx.x + s];
            __syncthreads();
        }
        if (threadIdx.x == 0) blksum[blockIdx.x] = lds[0];
        return;
    }
    int t = (blockIdx.x - NBLK) * 256 + threadIdx.x;
    if (t < 51 * WP) {
        int i = t / WP, j = t % WP;
        float a = 0.f;
        if (j < OUT_CH)
            for (int k = 0; k < HID; ++k) a += We1[i * HID + k] * Wc[k * WP + j];
        Mc[t] = a;
    } else if (t < 51 * WP + 51) {
        int j = t - 51 * WP;
        float a = 0.f;
        for (int k = 0; k < HID; ++k) a += be1[k] * Wc[k * WP + j];
        cc[j] = a;
    } else if (t < 51 * WP + 102) {
        int j = t - (51 * WP + 51);
        float a = 0.f;
        for (int k = 0; k < HID; ++k) a += b1[k] * Wout[k * OUT_CH + j];
        dd[j] = a + bout[j];
    }
}

// ---------- scan3 with inlined block-offset scan ----------
__global__ void k_scan3m(const int* __restrict__ deg, const int* __restrict__ blksum,
                         int* __restrict__ row_start, int* __restrict__ cursor) {
    __shared__ int lds[256];
    __shared__ int s_off;
    int tid = threadIdx.x;
    int v2 = (tid < NBLK) ? blksum[tid] : 0;
    lds[tid] = v2;
    __syncthreads();
    for (int s = 1; s < 256; s <<= 1) {
        int t = (tid >= s) ? lds[tid - s] : 0;
        __syncthreads();
        lds[tid] += t;
        __syncthreads();
    }
    if (tid == 0) s_off = (blockIdx.x == 0) ? 0 : lds[blockIdx.x - 1];
    __syncthreads();
    int boff = s_off;
    int i = blockIdx.x * 256 + tid;
    int v = (i < N_NODES) ? deg[i] : 0;
    lds[tid] = v;
    __syncthreads();
    for (int s = 1; s < 256; s <<= 1) {
        int t = (tid >= s) ? lds[tid - s] : 0;
        __syncthreads();
        lds[tid] += t;
        __syncthreads();
    }
    if (i < N_NODES) {
        int ex = boff + lds[tid] - v;
        row_start[i] = ex;
        cursor[i] = ex;
    }
    if (blockIdx.x == 0 && tid == 0) row_start[N_NODES] = N_EDGES;
}

// ---------- fill: single int2{src, eid} 8B scatter per edge ----------
__global__ void k_fill(const int* __restrict__ ei, int* __restrict__ cursor,
                       int2* __restrict__ pairs) {
    int e = blockIdx.x * 256 + threadIdx.x;
    if (e >= N_EDGES) return;
    int src = ei[e];
    int dst = ei[N_EDGES + e];
    int pos = atomicAdd(&cursor[dst], 1);
    pairs[pos] = make_int2(src, e);
}

// ---------- S aggregation: S[n] = sum_{e: dst=n} edge_attr[e] ----------
// 16-edge batched gather: 4 independent float4 loads in flight before any use
// (one random-access latency per 16 edges, not per 4).
__global__ void k_agg_S(const float* __restrict__ ea, const int2* __restrict__ pairs,
                        const int* __restrict__ row_start, float* __restrict__ S) {
    int n = blockIdx.x * 4 + (threadIdx.x >> 6);
    if (n >= N_NODES) return;
    int lane = threadIdx.x & 63;
    int g = lane >> 4, sub = lane & 15;
    bool act = sub < 13;
    int n0 = row_start[n], n1 = row_start[n + 1];
    float4 acc = make_float4(0.f, 0.f, 0.f, 0.f);
    for (int base = n0; base < n1; base += 64) {
        int cnt = min(64, n1 - base);
        int eid_l = (base + lane < n1) ? pairs[base + lane].y : 0;
        for (int t = 0; t < cnt; t += 16) {
            int i0 = t + g, i1 = t + 4 + g, i2 = t + 8 + g, i3 = t + 12 + g;
            bool k0 = i0 < cnt, k1 = i1 < cnt, k2 = i2 < cnt, k3 = i3 < cnt;
            int e0 = __shfl(eid_l, k0 ? i0 : 0);
            int e1 = __shfl(eid_l, k1 ? i1 : 0);
            int e2 = __shfl(eid_l, k2 ? i2 : 0);
            int e3 = __shfl(eid_l, k3 ? i3 : 0);
            float4 z = make_float4(0.f, 0.f, 0.f, 0.f);
            float4 v0 = z, v1 = z, v2 = z, v3 = z;
            if (k0 && act) v0 = *(const float4*)(ea + (size_t)e0 * EDIM + sub * 4);
            if (k1 && act) v1 = *(const float4*)(ea + (size_t)e1 * EDIM + sub * 4);
            if (k2 && act) v2 = *(const float4*)(ea + (size_t)e2 * EDIM + sub * 4);
            if (k3 && act) v3 = *(const float4*)(ea + (size_t)e3 * EDIM + sub * 4);
            if (sub == 12) { v0.w = 0.f; v1.w = 0.f; v2.w = 0.f; v3.w = 0.f; }
            acc.x += (v0.x + v1.x) + (v2.x + v3.x);
            acc.y += (v0.y + v1.y) + (v2.y + v3.y);
            acc.z += (v0.z + v1.z) + (v2.z + v3.z);
            acc.w += (v0.w + v1.w) + (v2.w + v3.w);
        }
    }
    acc.x += __shfl_xor(acc.x, 16); acc.y += __shfl_xor(acc.y, 16);
    acc.z += __shfl_xor(acc.z, 16); acc.w += __shfl_xor(acc.w, 16);
    acc.x += __shfl_xor(acc.x, 32); acc.y += __shfl_xor(acc.y, 32);
    acc.z += __shfl_xor(acc.z, 32); acc.w += __shfl_xor(acc.w, 32);
    if (lane < 13)
        *(float4*)(S + (size_t)n * SSTR + lane * 4) = acc;
}

// ---------- h aggregation: hacc[n] += sum_{e: dst=n} y[src[e]] ----------
// 16-edge batched gather: 4 independent uint4 loads in flight before any use.
__global__ void k_agg_h(const uint4* __restrict__ yb4, const int2* __restrict__ pairs,
                        const int* __restrict__ row_start, float* __restrict__ hacc) {
    int n = blockIdx.x * 4 + (threadIdx.x >> 6);
    if (n >= N_NODES) return;
    int lane = threadIdx.x & 63;
    int g = lane >> 4, s = lane & 15;
    int n0 = row_start[n], n1 = row_start[n + 1];
    float acc[8];
#pragma unroll
    for (int j = 0; j < 8; ++j) acc[j] = 0.f;
    for (int base = n0; base < n1; base += 64) {
        int cnt = min(64, n1 - base);
        int s_l = (base + lane < n1) ? pairs[base + lane].x : 0;
        for (int t = 0; t < cnt; t += 16) {
            int i0 = t + g, i1 = t + 4 + g, i2 = t + 8 + g, i3 = t + 12 + g;
            bool k0 = i0 < cnt, k1 = i1 < cnt, k2 = i2 < cnt, k3 = i3 < cnt;
            int s0 = __shfl(s_l, k0 ? i0 : 0);
            int s1 = __shfl(s_l, k1 ? i1 : 0);
            int s2 = __shfl(s_l, k2 ? i2 : 0);
            int s3 = __shfl(s_l, k3 ? i3 : 0);
            uint4 z = make_uint4(0u, 0u, 0u, 0u);
            uint4 v0 = z, v1 = z, v2 = z, v3 = z;
            if (k0) v0 = yb4[(size_t)s0 * 16 + s];
            if (k1) v1 = yb4[(size_t)s1 * 16 + s];
            if (k2) v2 = yb4[(size_t)s2 * 16 + s];
            if (k3) v3 = yb4[(size_t)s3 * 16 + s];
            acc[0] += (bflo(v0.x) + bflo(v1.x)) + (bflo(v2.x) + bflo(v3.x));
            acc[1] += (bfhi(v0.x) + bfhi(v1.x)) + (bfhi(v2.x) + bfhi(v3.x));
            acc[2] += (bflo(v0.y) + bflo(v1.y)) + (bflo(v2.y) + bflo(v3.y));
            acc[3] += (bfhi(v0.y) + bfhi(v1.y)) + (bfhi(v2.y) + bfhi(v3.y));
            acc[4] += (bflo(v0.z) + bflo(v1.z)) + (bflo(v2.z) + bflo(v3.z));
            acc[5] += (bfhi(v0.z) + bfhi(v1.z)) + (bfhi(v2.z) + bfhi(v3.z));
            acc[6] += (bflo(v0.w) + bflo(v1.w)) + (bflo(v2.w) + bflo(v3.w));
            acc[7] += (bfhi(v0.w) + bfhi(v1.w)) + (bfhi(v2.w) + bfhi(v3.w));
        }
    }
#pragma unroll
    for (int j = 0; j < 8; ++j) {
        acc[j] += __shfl_xor(acc[j], 16);
        acc[j] += __shfl_xor(acc[j], 32);
    }
    if (lane < 16) {
        float4* hp = (float4*)(hacc + (size_t)n * HID + lane * 8);
        float4 a = hp[0], b = hp[1];
        a.x += acc[0]; a.y += acc[1]; a.z += acc[2]; a.w += acc[3];
        b.x += acc[4]; b.y += acc[5]; b.z += acc[6]; b.w += acc[7];
        hp[0] = a; hp[1] = b;
    }
}

// ---------- out aggregation: out[n] += sum_{e: dst=n} w[src[e]] ----------
// 16-edge batched gather: 2 independent uint4 loads in flight before any use.
__global__ void k_agg_out(const uint4* __restrict__ wb4, const int2* __restrict__ pairs,
                          const int* __restrict__ row_start, float* __restrict__ out) {
    int n = blockIdx.x * 4 + (threadIdx.x >> 6);
    if (n >= N_NODES) return;
    int lane = threadIdx.x & 63;
    int g = lane >> 3, s = lane & 7;
    int n0 = row_start[n], n1 = row_start[n + 1];
    float acc[8];
#pragma unroll
    for (int j = 0; j < 8; ++j) acc[j] = 0.f;
    for (int base = n0; base < n1; base += 64) {
        int cnt = min(64, n1 - base);
        int s_l = (base + lane < n1) ? pairs[base + lane].x : 0;
        for (int t = 0; t < cnt; t += 16) {
            int i0 = t + g, i1 = t + 8 + g;
            bool k0 = i0 < cnt, k1 = i1 < cnt;
            int s0 = __shfl(s_l, k0 ? i0 : 0);
            int s1 = __shfl(s_l, k1 ? i1 : 0);
            uint4 z = make_uint4(0u, 0u, 0u, 0u);
            uint4 v0 = z, v1 = z;
            if (k0) v0 = wb4[(size_t)s0 * 8 + s];
            if (k1) v1 = wb4[(size_t)s1 * 8 + s];
            acc[0] += bflo(v0.x) + bflo(v1.x);
            acc[1] += bfhi(v0.x) + bfhi(v1.x);
            acc[2] += bflo(v0.y) + bflo(v1.y);
            acc[3] += bfhi(v0.y) + bfhi(v1.y);
            acc[4] += bflo(v0.z) + bflo(v1.z);
            acc[5] += bfhi(v0.z) + bfhi(v1.z);
            acc[6] += bflo(v0.w) + bflo(v1.w);
            acc[7] += bfhi(v0.w) + bfhi(v1.w);
        }
    }
#pragma unroll
    for (int j = 0; j < 8; ++j) {
        acc[j] += __shfl_xor(acc[j], 8);
        acc[j] += __shfl_xor(acc[j], 16);
        acc[j] += __shfl_xor(acc[j], 32);
    }
    if (lane < 8) {
#pragma unroll
        for (int j = 0; j < 8; ++j) {
            int ch = lane * 8 + j;
            if (ch < OUT_CH) out[(size_t)n * OUT_CH + ch] += acc[j];
        }
    }
}

// ---------- layer-0 tiled GEMM: y(bf16) = x@W0 ; hacc = y + S@M0 + (deg+1)*c0 + b0 ----------
__global__ __launch_bounds__(256, 4) void k_layer0(
        const float* __restrict__ x, const float* __restrict__ W0,
        const float* __restrict__ b0, const float* __restrict__ S,
        const int* __restrict__ deg, const float* __restrict__ M0,
        const float* __restrict__ c0,
        unsigned int* __restrict__ yb, float* __restrict__ hacc) {
    __shared__ float aT[64 * LSTR];   // 17,408 B
    int tid = threadIdx.x;
    int r_base = blockIdx.x * 64;
    int cg = tid & 15, rg = tid >> 4;
    int c = cg * 8, r0 = rg * 4;

    float4 accA[4], accB[4];
#pragma unroll
    for (int i = 0; i < 4; ++i) {
        accA[i] = make_float4(0.f, 0.f, 0.f, 0.f);
        accB[i] = make_float4(0.f, 0.f, 0.f, 0.f);
    }

    // ---- x phases: k = 0..150 in chunks of 64 ----
    for (int p = 0; p < 3; ++p) {
        int koff = p * 64;
        int chunk = min(64, IN_CH - koff);
        __syncthreads();
        for (int idx = tid; idx < 64 * 64; idx += 256) {
            int r = idx >> 6, kk = idx & 63;
            if (kk >= chunk) continue;
            int row = r_base + r;
            aT[kk * LSTR + r] = (row < N_NODES) ? x[(size_t)row * IN_CH + koff + kk] : 0.f;
        }
        __syncthreads();
#pragma unroll 4
        for (int kk = 0; kk < chunk; ++kk) {
            int k = koff + kk;
            float4 wv0 = *(const float4*)(W0 + k * HID + c);
            float4 wv1 = *(const float4*)(W0 + k * HID + c + 4);
            float4 a0 = *(const float4*)(&aT[kk * LSTR + r0]);
            float ar[4] = {a0.x, a0.y, a0.z, a0.w};
#pragma unroll
            for (int i = 0; i < 4; ++i) {
                accA[i].x += ar[i] * wv0.x; accA[i].y += ar[i] * wv0.y;
                accA[i].z += ar[i] * wv0.z; accA[i].w += ar[i] * wv0.w;
                accB[i].x += ar[i] * wv1.x; accB[i].y += ar[i] * wv1.y;
                accB[i].z += ar[i] * wv1.z; accB[i].w += ar[i] * wv1.w;
            }
        }
    }

    // ---- store y as bf16 ----
#pragma unroll
    for (int i = 0; i < 4; ++i) {
        int row = r_base + r0 + i;
        if (row < N_NODES) {
            uint4 pk;
            pk.x = f2bf(accA[i].x) | (f2bf(accA[i].y) << 16);
            pk.y = f2bf(accA[i].z) | (f2bf(accA[i].w) << 16);
            pk.z = f2bf(accB[i].x) | (f2bf(accB[i].y) << 16);
            pk.w = f2bf(accB[i].z) | (f2bf(accB[i].w) << 16);
            *(uint4*)(yb + (size_t)row * 64 + (c >> 1)) = pk;
        }
    }

    // ---- S phase: k = 0..50 ----
    __syncthreads();
    for (int idx = tid; idx < 64 * 64; idx += 256) {
        int r = idx >> 6, kk = idx & 63;
        if (kk >= EDIM) continue;
        int row = r_base + r;
        aT[kk * LSTR + r] = (row < N_NODES) ? S[(size_t)row * SSTR + kk] : 0.f;
    }
    __syncthreads();
#pragma unroll 4
    for (int kk = 0; kk < EDIM; ++kk) {
        float4 wv0 = *(const float4*)(M0 + kk * HID + c);
        float4 wv1 = *(const float4*)(M0 + kk * HID + c + 4);
        float4 a0 = *(const float4*)(&aT[kk * LSTR + r0]);
        float ar[4] = {a0.x, a0.y, a0.z, a0.w};
#pragma unroll
        for (int i = 0; i < 4; ++i) {
            accA[i].x += ar[i] * wv0.x; accA[i].y += ar[i] * wv0.y;
            accA[i].z += ar[i] * wv0.z; accA[i].w += ar[i] * wv0.w;
            accB[i].x += ar[i] * wv1.x; accB[i].y += ar[i] * wv1.y;
            accB[i].z += ar[i] * wv1.z; accB[i].w += ar[i] * wv1.w;
        }
    }

    // ---- epilogue: hacc = acc + (deg+1)*c0 + b0 (fp32) ----
    float4 cv0 = *(const float4*)(c0 + c);
    float4 cv1 = *(const float4*)(c0 + c + 4);
    float4 bv0 = *(const float4*)(b0 + c);
    float4 bv1 = *(const float4*)(b0 + c + 4);
#pragma unroll
    for (int i = 0; i < 4; ++i) {
        int row = r_base + r0 + i;
        if (row < N_NODES) {
            float d1 = (float)(deg[row] + 1);
            float4 vA = accA[i], vB = accB[i];
            vA.x += d1 * cv0.x + bv0.x; vA.y += d1 * cv0.y + bv0.y;
            vA.z += d1 * cv0.z + bv0.z; vA.w += d1 * cv0.w + bv0.w;
            vB.x += d1 * cv1.x + bv1.x; vB.y += d1 * cv1.y + bv1.y;
            vB.z += d1 * cv1.z + bv1.z; vB.w += d1 * cv1.w + bv1.w;
            *(float4*)(hacc + (size_t)row * HID + c) = vA;
            *(float4*)(hacc + (size_t)row * HID + c + 4) = vB;
        }
    }
}

// ---------- layer-1 tiled GEMM: w(bf16) = hacc@Wc ; out = w + S@Mc + (deg+1)*cc + dd ----------
__global__ __launch_bounds__(256, 4) void k_layer1(
        const float* __restrict__ hacc, const float* __restrict__ Wc,
        const float* __restrict__ S, const int* __restrict__ deg,
        const float* __restrict__ Mc, const float* __restrict__ cc,
        const float* __restrict__ dd,
        unsigned int* __restrict__ wb, float* __restrict__ out) {
    __shared__ float aT[64 * LSTR];
    int tid = threadIdx.x;
    int r_base = blockIdx.x * 64;
    int cg = tid & 15, rg = tid >> 4;
    int c = cg * 4, r0 = rg * 4;

    float4 acc[4];
#pragma unroll
    for (int i = 0; i < 4; ++i) acc[i] = make_float4(0.f, 0.f, 0.f, 0.f);

    // ---- h phases: k = 0..127 in chunks of 64 ----
    for (int p = 0; p < 2; ++p) {
        int koff = p * 64;
        __syncthreads();
        for (int idx = tid; idx < 64 * 64; idx += 256) {
            int r = idx >> 6, kk = idx & 63;
            int row = r_base + r;
            aT[kk * LSTR + r] = (row < N_NODES) ? hacc[(size_t)row * HID + koff + kk] : 0.f;
        }
        __syncthreads();
#pragma unroll 4
        for (int kk = 0; kk < 64; ++kk) {
            int k = koff + kk;
            float4 wv = *(const float4*)(Wc + k * WP + c);
            float4 a0 = *(const float4*)(&aT[kk * LSTR + r0]);
            float ar[4] = {a0.x, a0.y, a0.z, a0.w};
#pragma unroll
            for (int i = 0; i < 4; ++i) {
                acc[i].x += ar[i] * wv.x; acc[i].y += ar[i] * wv.y;
                acc[i].z += ar[i] * wv.z; acc[i].w += ar[i] * wv.w;
            }
        }
    }

    // ---- store w as bf16 (padded 64) ----
#pragma unroll
    for (int i = 0; i < 4; ++i) {
        int row = r_base + r0 + i;
        if (row < N_NODES) {
            uint2 pk;
            pk.x = f2bf(acc[i].x) | (f2bf(acc[i].y) << 16);
            pk.y = f2bf(acc[i].z) | (f2bf(acc[i].w) << 16);
            *(uint2*)(wb + (size_t)row * 32 + (c >> 1)) = pk;
        }
    }

    // ---- S phase ----
    __syncthreads();
    for (int idx = tid; idx < 64 * 64; idx += 256) {
        int r = idx >> 6, kk = idx & 63;
        if (kk >= EDIM) continue;
        int row = r_base + r;
        aT[kk * LSTR + r] = (row < N_NODES) ? S[(size_t)row * SSTR + kk] : 0.f;
    }
    __syncthreads();
#pragma unroll 4
    for (int kk = 0; kk < EDIM; ++kk) {
        float4 wv = *(const float4*)(Mc + kk * WP + c);
        float4 a0 = *(const float4*)(&aT[kk * LSTR + r0]);
        float ar[4] = {a0.x, a0.y, a0.z, a0.w};
#pragma unroll
        for (int i = 0; i < 4; ++i) {
            acc[i].x += ar[i] * wv.x; acc[i].y += ar[i] * wv.y;
            acc[i].z += ar[i] * wv.z; acc[i].w += ar[i] * wv.w;
        }
    }

    // ---- epilogue: out = acc + (deg+1)*cc + dd, cols < 51 ----
    if (c < OUT_CH) {
        float cv[4], dv[4];
#pragma unroll
        for (int j = 0; j < 4; ++j) {
            int col = c + j;
            cv[j] = (col < OUT_CH) ? cc[col] : 0.f;
            dv[j] = (col < OUT_CH) ? dd[col] : 0.f;
        }
#pragma unroll
        for (int i = 0; i < 4; ++i) {
            int row = r_base + r0 + i;
            if (row < N_NODES) {
                float d1 = (float)(deg[row] + 1);
                const float* ap = (const float*)&acc[i];
#pragma unroll
                for (int j = 0; j < 4; ++j) {
                    int col = c + j;
                    if (col < OUT_CH)
                        out[(size_t)row * OUT_CH + col] = ap[j] + d1 * cv[j] + dv[j];
                }
            }
        }
    }
}

extern "C" void kernel_launch(void* const* d_in, const int* in_sizes, int n_in,
                              void* d_out, int out_size, void* d_ws, size_t ws_size,
                              hipStream_t stream) {
    const float* x    = (const float*)d_in[0];
    const float* ea   = (const float*)d_in[1];
    const float* We0  = (const float*)d_in[2];
    const float* be0  = (const float*)d_in[3];
    const float* W0   = (const float*)d_in[4];
    const float* b0   = (const float*)d_in[5];
    const float* We1  = (const float*)d_in[6];
    const float* be1  = (const float*)d_in[7];
    const float* W1   = (const float*)d_in[8];
    const float* b1   = (const float*)d_in[9];
    const float* Wout = (const float*)d_in[10];
    const float* bout = (const float*)d_in[11];
    const int*   ei   = (const int*)d_in[12];
    float* out = (float*)d_out;

    char* p = (char*)d_ws;
    auto alloc = [&](size_t bytes) {
        char* r = p;
        p += (bytes + 255) & ~(size_t)255;
        return r;
    };
    float* S         = (float*)alloc((size_t)N_NODES * SSTR * 4);    // 10.4 MB
    int*   deg       = (int*)  alloc((size_t)N_NODES * 4);
    int*   row_start = (int*)  alloc((size_t)(N_NODES + 1) * 4);
    int*   cursor    = (int*)  alloc((size_t)N_NODES * 4);
    int*   blksum    = (int*)  alloc((size_t)NBLK * 4);
    int2*  pairs     = (int2*) alloc((size_t)N_EDGES * 8);           // 6.4 MB {src, eid}
    unsigned int* yb = (unsigned int*)alloc((size_t)N_NODES * 64 * 4);  // y bf16: 12.8 MB
    float* hacc      = (float*)alloc((size_t)N_NODES * HID * 4);     // 25.6 MB
    unsigned int* wb = (unsigned int*)alloc((size_t)N_NODES * 32 * 4);  // w bf16: 6.4 MB
    float* M0        = (float*)alloc(51 * 128 * 4);
    float* c0        = (float*)alloc(128 * 4);
    float* Wc        = (float*)alloc(128 * WP * 4);
    float* Mc        = (float*)alloc(51 * WP * 4);
    float* cc        = (float*)alloc(51 * 4);
    float* dd        = (float*)alloc(51 * 4);

    hipMemsetAsync(deg, 0, (size_t)N_NODES * 4, stream);

    k_hist_kw1<<<EBLK + KW1_B, 256, 0, stream>>>(ei, deg, We0, W0, be0, W1, Wout, M0, c0, Wc);
    k_scan1_kw2<<<NBLK + KW2_B, 256, 0, stream>>>(deg, blksum, We1, be1, b1, Wout, bout,
                                                  Wc, Mc, cc, dd);
    k_scan3m<<<NBLK, 256, 0, stream>>>(deg, blksum, row_start, cursor);
    k_fill<<<EBLK, 256, 0, stream>>>(ei, cursor, pairs);

    // S aggregation (batched gather)
    k_agg_S<<<(N_NODES + 3) / 4, 256, 0, stream>>>(ea, pairs, row_start, S);

    // layer 0
    k_layer0<<<(N_NODES + 63) / 64, 256, 0, stream>>>(x, W0, b0, S, deg, M0, c0, yb, hacc);
    k_agg_h<<<(N_NODES + 3) / 4, 256, 0, stream>>>((const uint4*)yb, pairs, row_start, hacc);

    // layer 1 + output projection
    k_layer1<<<(N_NODES + 63) / 64, 256, 0, stream>>>(hacc, Wc, S, deg, Mc, cc, dd, wb, out);
    k_agg_out<<<(N_NODES + 3) / 4, 256, 0, stream>>>((const uint4*)wb, pairs, row_start, out);
}